// Round 1
// baseline (24.216 us; speedup 1.0000x reference)
//
#include <hip/hip_runtime.h>

// Problem constants (from reference)
#define BSZ     64
#define NN      64
#define PAD_LEN 64
#define DD      128
#define N_ITEMS (BSZ * NN)   // 4096

// One wave (64 lanes) per output item.
// lane l accumulates float2 at columns [2l, 2l+1] of the D=128 row.
// Each emb row read = 64 lanes x 8B = 512B fully-coalesced transaction.
__global__ __launch_bounds__(256) void avg_encoder_kernel(
    const int*   __restrict__ ids,       // [BSZ*NN]
    const int*   __restrict__ tokens,    // [N_I, PAD_LEN]
    const float* __restrict__ lens,      // [N_I]
    const float* __restrict__ emb,       // [VOCAB, DD]
    float*       __restrict__ out)       // [BSZ*NN, DD]
{
    const int lane = threadIdx.x & 63;
    const int wave = threadIdx.x >> 6;                 // 0..3
    const int item = blockIdx.x * 4 + wave;            // 0..4095
    if (item >= N_ITEMS) return;

    const int   id      = ids[item];                   // wave-uniform
    const float inv_len = 1.0f / lens[id];
    const int*  trow    = tokens + (long)id * PAD_LEN;

    float accx = 0.0f, accy = 0.0f;

    #pragma unroll 8
    for (int k = 0; k < PAD_LEN; ++k) {
        const int tok = trow[k];                       // wave-uniform, L1 broadcast
        const float2 e =
            *reinterpret_cast<const float2*>(emb + (long)tok * DD + lane * 2);
        accx += e.x;
        accy += e.y;
    }

    float2 r;
    r.x = accx * inv_len;
    r.y = accy * inv_len;
    *reinterpret_cast<float2*>(out + (long)item * DD + lane * 2) = r;
}

extern "C" void kernel_launch(void* const* d_in, const int* in_sizes, int n_in,
                              void* d_out, int out_size, void* d_ws, size_t ws_size,
                              hipStream_t stream) {
    const int*   ids    = (const int*)  d_in[0];
    const int*   tokens = (const int*)  d_in[1];
    const float* lens   = (const float*)d_in[2];
    const float* emb    = (const float*)d_in[3];
    float*       out    = (float*)d_out;

    const int items_per_block = 4;                     // 256 threads = 4 waves
    const int grid = (N_ITEMS + items_per_block - 1) / items_per_block;  // 1024
    avg_encoder_kernel<<<grid, 256, 0, stream>>>(ids, tokens, lens, emb, out);
}